// Round 1
// baseline (1202.641 us; speedup 1.0000x reference)
//
#include <hip/hip_runtime.h>
#include <hip/hip_bf16.h>

// ---------- types ----------
typedef __attribute__((ext_vector_type(8))) short     bf16x8;   // 8 bf16 in 4 VGPRs (MFMA A/B frag)
typedef __attribute__((ext_vector_type(4))) float     f32x4;    // MFMA C/D frag
typedef __attribute__((ext_vector_type(4))) unsigned short ushort4_t;

// B=512, T=256, D=256, H=128, 4H=512
#define BSZ   512
#define TSZ   256
#define DSZ   256
#define HSZ   128
#define G4    512   // 4*H
#define OUT1  16777216  // B*T*H

// ---------- helpers ----------
__device__ inline unsigned short f2bf(float f) {
  union { float f; unsigned int u; } v; v.f = f;
  unsigned int r = (v.u + 0x7FFFu + ((v.u >> 16) & 1u)) >> 16;
  return (unsigned short)r;
}
__device__ inline float bf2f(unsigned short s) {
  union { unsigned int u; float f; } v; v.u = ((unsigned int)s) << 16;
  return v.f;
}

__device__ inline float xw_load(const float* p, long i) { return p[i]; }
__device__ inline float xw_load(const unsigned short* p, long i) { return bf2f(p[i]); }
__device__ inline void xw_store(float* p, long i, float v) { p[i] = v; }
__device__ inline void xw_store(unsigned short* p, long i, float v) { p[i] = f2bf(v); }

__device__ inline float sig_fast(float x)  { return 1.0f / (1.0f + __expf(-x)); }
__device__ inline float tanh_fast(float x) { return 1.0f - 2.0f / (__expf(2.0f * x) + 1.0f); }

// ---------- kernel 1: xw[B*T, 4H] = x[B*T, D] @ Wx.T + b (bf16 MFMA, fp32 acc) ----------
// tile: 64(M) x 64(N), K=256 staged whole in LDS in fragment-linear layout.
// frag layouts (guide-verified): A[m=lane&15][k=(lane>>4)*8+j]; B[n=lane&15][k=(lane>>4)*8+j];
// C/D: col=lane&15, row=(lane>>4)*4+r.
template <class XWT>
__global__ __launch_bounds__(256)
void gemm_xw(const float* __restrict__ x, const float* __restrict__ Wx,
             const float* __restrict__ bias, XWT* __restrict__ xw) {
  // [c(8)][tile(4)][lane(64)][j(8)] bf16 each = 16384 shorts = 32 KB each
  __shared__ unsigned short aF[16384];
  __shared__ unsigned short bF[16384];

  const int tid   = threadIdx.x;
  const long mBase = (long)blockIdx.x * 64;
  const int  nBase = blockIdx.y * 64;

  const float* aSrc = x  + mBase * DSZ;          // 64 contiguous rows of 256 floats
  const float* bSrc = Wx + (long)nBase * DSZ;

#pragma unroll
  for (int i = 0; i < 16; ++i) {
    int e  = i * 1024 + tid * 4;                  // element index in 64x256 tile
    int m  = e >> 8, k = e & 255;
    int c  = k >> 5, kk = k & 31;
    int lane = (m & 15) | ((kk >> 3) << 4);
    int j  = kk & 7;                              // 0 or 4
    int mt = m >> 4;
    int dst = (((c << 2) + mt) * 64 + lane) * 8 + j;
    float4 va = *(const float4*)(aSrc + e);
    float4 vb = *(const float4*)(bSrc + e);
    ushort4_t pa, pb;
    pa.x = f2bf(va.x); pa.y = f2bf(va.y); pa.z = f2bf(va.z); pa.w = f2bf(va.w);
    pb.x = f2bf(vb.x); pb.y = f2bf(vb.y); pb.z = f2bf(vb.z); pb.w = f2bf(vb.w);
    *(ushort4_t*)&aF[dst] = pa;
    *(ushort4_t*)&bF[dst] = pb;
  }
  __syncthreads();

  const int w = tid >> 6, lane = tid & 63;
  f32x4 acc[4];
#pragma unroll
  for (int nt = 0; nt < 4; ++nt) acc[nt] = (f32x4){0.f, 0.f, 0.f, 0.f};

#pragma unroll
  for (int c = 0; c < 8; ++c) {
    bf16x8 av = *(const bf16x8*)&aF[(((c << 2) + w) * 64 + lane) * 8];
#pragma unroll
    for (int nt = 0; nt < 4; ++nt) {
      bf16x8 bv = *(const bf16x8*)&bF[(((c << 2) + nt) * 64 + lane) * 8];
      acc[nt] = __builtin_amdgcn_mfma_f32_16x16x32_bf16(av, bv, acc[nt], 0, 0, 0);
    }
  }

  const int colLoc = lane & 15, rowQ = lane >> 4;
#pragma unroll
  for (int nt = 0; nt < 4; ++nt) {
    int n = nBase + nt * 16 + colLoc;
    float bv = bias[n];
#pragma unroll
    for (int r = 0; r < 4; ++r) {
      long m = mBase + w * 16 + rowQ * 4 + r;
      xw_store(xw, m * (long)G4 + n, acc[nt][r] + bv);
    }
  }
}

// ---------- kernel 2: recurrent scan, fp32 VALU ----------
// 256 blocks x 512 threads; block owns 2 batch elems; thread t owns gate row t
// with Wh[t,0:128] resident in 128 VGPRs. h in LDS (broadcast reads).
template <class XWT>
__global__ __launch_bounds__(512, 2)
void lstm_rec(const XWT* __restrict__ xw, const float* __restrict__ Wh,
              float* __restrict__ outH, float* __restrict__ outC,
              float* __restrict__ outP) {
  __shared__ float hid_s[2][HSZ];
  __shared__ float gates_s[2][G4];

  const int t0 = threadIdx.x;          // gate index 0..511
  const int b0 = blockIdx.x * 2;

  // Wh row -> registers (one-time; L2-hot after first blocks)
  float4 wh[32];
  const float4* whp = (const float4*)(Wh + (long)t0 * HSZ);
#pragma unroll
  for (int q = 0; q < 32; ++q) wh[q] = whp[q];

  if (t0 < 256) hid_s[t0 >> 7][t0 & 127] = 0.0f;
  float cel = 0.0f, pog = 0.0f;        // live in update threads (<256)

  const long xb0 = (long)b0 * TSZ * G4 + t0;
  const long xb1 = (long)(b0 + 1) * TSZ * G4 + t0;
  float xv0 = xw_load(xw, xb0);
  float xv1 = xw_load(xw, xb1);

  const bool isTanh = (t0 >= 384);
  __syncthreads();

  for (int t = 0; t < TSZ; ++t) {
    float acc0 = xv0, acc1 = xv1;
    // prefetch next step's xw to hide HBM latency behind the FMA loop
    int tn = (t < TSZ - 1) ? (t + 1) : (TSZ - 1);
    float nx0 = xw_load(xw, xb0 + (long)tn * G4);
    float nx1 = xw_load(xw, xb1 + (long)tn * G4);

    const float4* h0 = (const float4*)hid_s[0];
    const float4* h1 = (const float4*)hid_s[1];
#pragma unroll
    for (int q = 0; q < 32; ++q) {
      float4 w4 = wh[q];
      float4 a  = h0[q];
      float4 b4 = h1[q];
      acc0 += w4.x * a.x;  acc1 += w4.x * b4.x;
      acc0 += w4.y * a.y;  acc1 += w4.y * b4.y;
      acc0 += w4.z * a.z;  acc1 += w4.z * b4.z;
      acc0 += w4.w * a.w;  acc1 += w4.w * b4.w;
    }

    float g0 = isTanh ? tanh_fast(acc0) : sig_fast(acc0);
    float g1 = isTanh ? tanh_fast(acc1) : sig_fast(acc1);
    gates_s[0][t0] = g0;
    gates_s[1][t0] = g1;
    __syncthreads();

    if (t0 < 256) {
      int bb = t0 >> 7, j = t0 & 127;
      float iv = gates_s[bb][j];
      float fv = gates_s[bb][j + 128];
      float ov = 0.85f * gates_s[bb][j + 256] + 0.15f * pog;
      float gv = gates_s[bb][j + 384];
      float c  = fv * cel + iv * gv;
      float h  = ov * tanh_fast(c);
      cel = c; pog = ov;
      hid_s[bb][j] = h;
      long o = ((long)(b0 + bb) * TSZ + t) * HSZ + j;
      outH[o] = h;
      outC[o] = c;
      outP[o] = ov;
    }
    __syncthreads();
    xv0 = nx0; xv1 = nx1;
  }
}

// ---------- launch ----------
extern "C" void kernel_launch(void* const* d_in, const int* in_sizes, int n_in,
                              void* d_out, int out_size, void* d_ws, size_t ws_size,
                              hipStream_t stream) {
  const float* x    = (const float*)d_in[0];
  const float* Wx   = (const float*)d_in[1];
  const float* Wh   = (const float*)d_in[2];
  const float* bias = (const float*)d_in[3];

  float* outH = (float*)d_out;
  float* outC = outH + OUT1;
  float* outP = outC + OUT1;

  dim3 g1(2048, 8), tb1(256);
  dim3 g2(256),     tb2(512);

  const size_t xwElems = (size_t)BSZ * TSZ * G4;          // 67,108,864
  if (ws_size >= xwElems * sizeof(float)) {
    float* xw = (float*)d_ws;
    gemm_xw<float><<<g1, tb1, 0, stream>>>(x, Wx, bias, xw);
    lstm_rec<float><<<g2, tb2, 0, stream>>>(xw, Wh, outH, outC, outP);
  } else {
    unsigned short* xw = (unsigned short*)d_ws;           // bf16 fallback
    gemm_xw<unsigned short><<<g1, tb1, 0, stream>>>(x, Wx, bias, xw);
    lstm_rec<unsigned short><<<g2, tb2, 0, stream>>>(xw, Wh, outH, outC, outP);
  }
}

// Round 2
// 733.826 us; speedup vs baseline: 1.6389x; 1.6389x over previous
//
#include <hip/hip_runtime.h>
#include <hip/hip_bf16.h>

// ---------- types ----------
typedef __attribute__((ext_vector_type(8))) short     bf16x8;   // MFMA A/B frag (4 VGPRs)
typedef __attribute__((ext_vector_type(4))) float     f32x4;    // MFMA C/D frag
typedef __attribute__((ext_vector_type(4))) unsigned short ushort4_t;

// B=512, T=256, D=256, H=128, 4H=512
#define BSZ   512
#define TSZ   256
#define DSZ   256
#define HSZ   128
#define G4    512
#define OUT1  16777216  // B*T*H

// ---------- helpers ----------
__device__ inline unsigned short f2bf(float f) {
  union { float f; unsigned int u; } v; v.f = f;
  unsigned int r = (v.u + 0x7FFFu + ((v.u >> 16) & 1u)) >> 16;
  return (unsigned short)r;
}
__device__ inline float bf2f(unsigned short s) {
  union { unsigned int u; float f; } v; v.u = ((unsigned int)s) << 16;
  return v.f;
}
__device__ inline float xw_load(const float* p, long i) { return p[i]; }
__device__ inline float xw_load(const unsigned short* p, long i) { return bf2f(p[i]); }
__device__ inline void xw_store(float* p, long i, float v) { p[i] = v; }
__device__ inline void xw_store(unsigned short* p, long i, float v) { p[i] = f2bf(v); }

__device__ inline float sig_fast(float x)  { return 1.0f / (1.0f + __expf(-x)); }
__device__ inline float tanh_fast(float x) { return 1.0f - 2.0f / (__expf(2.0f * x) + 1.0f); }

// ---------- kernel 1: xw[B*T, 4H] = x[B*T, D] @ Wx.T + b (bf16 MFMA, fp32 acc) ----------
// Unchanged from R1 except launch grid is swapped (N fastest) for x L2 reuse.
template <class XWT>
__global__ __launch_bounds__(256)
void gemm_xw(const float* __restrict__ x, const float* __restrict__ Wx,
             const float* __restrict__ bias, XWT* __restrict__ xw) {
  __shared__ unsigned short aF[16384];
  __shared__ unsigned short bF[16384];

  const int tid   = threadIdx.x;
  const long mBase = (long)blockIdx.y * 64;   // M now on y (slow)
  const int  nBase = blockIdx.x * 64;         // N on x (fast) -> same-M blocks adjacent

  const float* aSrc = x  + mBase * DSZ;
  const float* bSrc = Wx + (long)nBase * DSZ;

#pragma unroll
  for (int i = 0; i < 16; ++i) {
    int e  = i * 1024 + tid * 4;
    int m  = e >> 8, k = e & 255;
    int c  = k >> 5, kk = k & 31;
    int lane = (m & 15) | ((kk >> 3) << 4);
    int j  = kk & 7;
    int mt = m >> 4;
    int dst = (((c << 2) + mt) * 64 + lane) * 8 + j;
    float4 va = *(const float4*)(aSrc + e);
    float4 vb = *(const float4*)(bSrc + e);
    ushort4_t pa, pb;
    pa.x = f2bf(va.x); pa.y = f2bf(va.y); pa.z = f2bf(va.z); pa.w = f2bf(va.w);
    pb.x = f2bf(vb.x); pb.y = f2bf(vb.y); pb.z = f2bf(vb.z); pb.w = f2bf(vb.w);
    *(ushort4_t*)&aF[dst] = pa;
    *(ushort4_t*)&bF[dst] = pb;
  }
  __syncthreads();

  const int w = tid >> 6, lane = tid & 63;
  f32x4 acc[4];
#pragma unroll
  for (int nt = 0; nt < 4; ++nt) acc[nt] = (f32x4){0.f, 0.f, 0.f, 0.f};

#pragma unroll
  for (int c = 0; c < 8; ++c) {
    bf16x8 av = *(const bf16x8*)&aF[(((c << 2) + w) * 64 + lane) * 8];
#pragma unroll
    for (int nt = 0; nt < 4; ++nt) {
      bf16x8 bv = *(const bf16x8*)&bF[(((c << 2) + nt) * 64 + lane) * 8];
      acc[nt] = __builtin_amdgcn_mfma_f32_16x16x32_bf16(av, bv, acc[nt], 0, 0, 0);
    }
  }

  const int colLoc = lane & 15, rowQ = lane >> 4;
#pragma unroll
  for (int nt = 0; nt < 4; ++nt) {
    int n = nBase + nt * 16 + colLoc;
    float bv = bias[n];
#pragma unroll
    for (int r = 0; r < 4; ++r) {
      long m = mBase + w * 16 + rowQ * 4 + r;
      xw_store(xw, m * (long)G4 + n, acc[nt][r] + bv);
    }
  }
}

// ---------- kernel 2: recurrent scan via MFMA ----------
// 256 blocks x 512 threads (8 waves). Block owns 2 batches (MFMA rows 0,1; rows 2-15 dead).
// Wave w owns gate columns {16w..16w+15} of each quadrant i/f/o/g as 4 N-tiles:
//   Wh B-frags resident in 64 VGPRs/lane (distributed across lanes -- the R1 fix).
// Per step: read h A-frags from LDS -> 16 MFMA -> in-register ifog update ->
// write h (bf16, A-frag layout) to the OTHER LDS buffer -> ONE __syncthreads.
template <class XWT>
__global__ __launch_bounds__(512, 2)
void lstm_rec_mfma(const XWT* __restrict__ xw, const float* __restrict__ Wh,
                   float* __restrict__ outH, float* __restrict__ outC,
                   float* __restrict__ outP) {
  __shared__ unsigned short h_lds[2 * 2048];   // [buf][c(4)][lane(64)][j(8)] bf16, 4KB/buf

  const int tid  = threadIdx.x;
  const int w    = tid >> 6;        // wave 0..7
  const int lane = tid & 63;
  const int p    = lane & 15;
  const int r16  = lane >> 4;       // 0..3
  const int b0   = blockIdx.x * 2;

  // Wh -> B-frags (one-time). B[n=lane&15][k=(lane>>4)*8+j], n = q*128 + w*16 + p.
  bf16x8 whF[4][4];                 // [quadrant q][k-chunk c]
#pragma unroll
  for (int q = 0; q < 4; ++q) {
#pragma unroll
    for (int c = 0; c < 4; ++c) {
      const float* src = Wh + ((q * 128 + w * 16 + p) * HSZ + c * 32 + r16 * 8);
      float4 lo = *(const float4*)src;
      float4 hi = *(const float4*)(src + 4);
      bf16x8 f;
      f[0] = (short)f2bf(lo.x); f[1] = (short)f2bf(lo.y);
      f[2] = (short)f2bf(lo.z); f[3] = (short)f2bf(lo.w);
      f[4] = (short)f2bf(hi.x); f[5] = (short)f2bf(hi.y);
      f[6] = (short)f2bf(hi.z); f[7] = (short)f2bf(hi.w);
      whF[q][c] = f;
    }
  }

  // zero both h buffers (rows 2-15 stay zero forever -> no NaN into MFMA)
  for (int i = tid; i < 2 * 2048; i += 512) h_lds[i] = 0;

  float cel0 = 0.f, cel1 = 0.f, pog0 = 0.f, pog1 = 0.f;

  // xw column index for this lane (lanes 16-63 duplicate lane&15 -> coalesced, no NaN)
  const long xcol = w * 16 + p;
  const long xrow0 = (long)(b0 + 0) * TSZ * G4 + xcol;
  const long xrow1 = (long)(b0 + 1) * TSZ * G4 + xcol;

  // prefetch t=0
  float xv[4][2];
#pragma unroll
  for (int q = 0; q < 4; ++q) {
    xv[q][0] = xw_load(xw, xrow0 + q * 128);
    xv[q][1] = xw_load(xw, xrow1 + q * 128);
  }

  __syncthreads();

  int buf = 0;
  for (int t = 0; t < TSZ; ++t) {
    // h A-frags from LDS (lane-linear -> ds_read_b128, broadcast-free)
    bf16x8 aF[4];
#pragma unroll
    for (int c = 0; c < 4; ++c)
      aF[c] = *(const bf16x8*)&h_lds[buf * 2048 + c * 512 + lane * 8];

    // prefetch next step's xw EARLY so the barrier's vmcnt drain is cheap
    const int tn = (t < TSZ - 1) ? (t + 1) : (TSZ - 1);
    float nxv[4][2];
#pragma unroll
    for (int q = 0; q < 4; ++q) {
      nxv[q][0] = xw_load(xw, xrow0 + (long)tn * G4 + q * 128);
      nxv[q][1] = xw_load(xw, xrow1 + (long)tn * G4 + q * 128);
    }

    // C-frags init with xw (rows 0,1 real; other rows garbage-but-finite)
    f32x4 acc[4];
#pragma unroll
    for (int q = 0; q < 4; ++q) {
      acc[q][0] = xv[q][0];
      acc[q][1] = xv[q][1];
      acc[q][2] = 0.f;
      acc[q][3] = 0.f;
    }

#pragma unroll
    for (int q = 0; q < 4; ++q)
#pragma unroll
      for (int c = 0; c < 4; ++c)
        acc[q] = __builtin_amdgcn_mfma_f32_16x16x32_bf16(aF[c], whF[q][c], acc[q], 0, 0, 0);

    // update (rows 0,1 live in lanes 0-15, regs 0,1; all lanes compute, only <16 store)
    float i0 = sig_fast(acc[0][0]), i1 = sig_fast(acc[0][1]);
    float f0 = sig_fast(acc[1][0]), f1 = sig_fast(acc[1][1]);
    float o0 = 0.85f * sig_fast(acc[2][0]) + 0.15f * pog0;
    float o1 = 0.85f * sig_fast(acc[2][1]) + 0.15f * pog1;
    float g0 = tanh_fast(acc[3][0]), g1 = tanh_fast(acc[3][1]);
    cel0 = f0 * cel0 + i0 * g0;
    cel1 = f1 * cel1 + i1 * g1;
    float h0 = o0 * tanh_fast(cel0);
    float h1 = o1 * tanh_fast(cel1);
    pog0 = o0; pog1 = o1;

    const int nbuf = buf ^ 1;
    if (lane < 16) {
      const int col = w * 16 + p;
      const long o0i = ((long)(b0 + 0) * TSZ + t) * HSZ + col;
      const long o1i = ((long)(b0 + 1) * TSZ + t) * HSZ + col;
      outH[o0i] = h0;  outC[o0i] = cel0;  outP[o0i] = o0;
      outH[o1i] = h1;  outC[o1i] = cel1;  outP[o1i] = o1;
      // h -> A-frag layout bf16 for next step
      const int c_  = col >> 5, kk = col & 31;
      const int lhi = (kk >> 3) << 4, j = kk & 7;
      h_lds[nbuf * 2048 + c_ * 512 + (0 | lhi) * 8 + j] = f2bf(h0);
      h_lds[nbuf * 2048 + c_ * 512 + (1 | lhi) * 8 + j] = f2bf(h1);
    }
    __syncthreads();   // single barrier per step (double-buffered h)

    buf = nbuf;
#pragma unroll
    for (int q = 0; q < 4; ++q) { xv[q][0] = nxv[q][0]; xv[q][1] = nxv[q][1]; }
  }
}

// ---------- launch ----------
extern "C" void kernel_launch(void* const* d_in, const int* in_sizes, int n_in,
                              void* d_out, int out_size, void* d_ws, size_t ws_size,
                              hipStream_t stream) {
  const float* x    = (const float*)d_in[0];
  const float* Wx   = (const float*)d_in[1];
  const float* Wh   = (const float*)d_in[2];
  const float* bias = (const float*)d_in[3];

  float* outH = (float*)d_out;
  float* outC = outH + OUT1;
  float* outP = outC + OUT1;

  dim3 g1(8, 2048), tb1(256);   // N fastest -> x fetched once, reused via L2
  dim3 g2(256),     tb2(512);

  const size_t xwElems = (size_t)BSZ * TSZ * G4;
  if (ws_size >= xwElems * sizeof(float)) {
    float* xwp = (float*)d_ws;
    gemm_xw<float><<<g1, tb1, 0, stream>>>(x, Wx, bias, xwp);
    lstm_rec_mfma<float><<<g2, tb2, 0, stream>>>(xwp, Wh, outH, outC, outP);
  } else {
    unsigned short* xwp = (unsigned short*)d_ws;  // bf16 fallback
    gemm_xw<unsigned short><<<g1, tb1, 0, stream>>>(x, Wx, bias, xwp);
    lstm_rec_mfma<unsigned short><<<g2, tb2, 0, stream>>>(xwp, Wh, outH, outC, outP);
  }
}